// Round 1
// baseline (723.566 us; speedup 1.0000x reference)
//
#include <hip/hip_runtime.h>
#include <math.h>

#define B_    8
#define CIN   512
#define H_    64
#define W_    64
#define COUT  64
#define ALPHA 8.3f

#define TH 8          // tile height (pixels)
#define TW 32         // tile width
#define CB 4          // channels staged per iteration
#define CS 2          // channel split across blocks
#define CHALF (CIN / CS)

// Each block: one (b, 32x8 pixel tile, c-half). 256 threads.
// Thread: og = tid>>6 -> 16 outputs [og*16, og*16+16); pid = tid&63 ->
// 4 pixels at (wl = pid&31, rows hb+2p, hb = pid>>5, p=0..3).
__global__ __launch_bounds__(256, 1)
void depthconv_kernel(const float* __restrict__ x,
                      const float* __restrict__ depth,
                      const float* __restrict__ weight,
                      float* __restrict__ out) {
    __shared__ float xs[CB][TH + 2][TW + 2];   // 4*10*34*4 = 5440 B
    __shared__ float ws[CB][COUT][9];          // 4*64*9*4  = 9216 B

    const int bx = blockIdx.x;
    const int cs = bx & 1;
    const int wt = (bx >> 1) & 1;
    const int ht = (bx >> 2) & 7;
    const int b  = bx >> 5;

    const int h0 = ht * TH;
    const int w0 = wt * TW;
    const int c0 = cs * CHALF;

    const int tid = threadIdx.x;
    const int og  = tid >> 6;      // output group 0..3
    const int pid = tid & 63;
    const int wl  = pid & 31;      // local col 0..31
    const int hb  = pid >> 5;      // base row 0..1

    // ---- gates: 4 pixels x 9 taps (matches reference: OOB depth = 0, but
    // x is 0 there anyway so the value is inert) ----
    float gate[4][9];
    const float* dptr = depth + (size_t)b * (H_ * W_);
#pragma unroll
    for (int p = 0; p < 4; ++p) {
        const int hh = h0 + hb + 2 * p;
        const int ww = w0 + wl;
        const float d0 = dptr[hh * W_ + ww];
#pragma unroll
        for (int i = 0; i < 3; ++i) {
#pragma unroll
            for (int j = 0; j < 3; ++j) {
                const int hn = hh + i - 1, wn = ww + j - 1;
                float dn = 0.f;
                if (hn >= 0 && hn < H_ && wn >= 0 && wn < W_)
                    dn = dptr[hn * W_ + wn];
                gate[p][i * 3 + j] = __expf(-ALPHA * fabsf(d0 - dn));
            }
        }
    }

    float acc[4][16];
#pragma unroll
    for (int p = 0; p < 4; ++p)
#pragma unroll
        for (int o = 0; o < 16; ++o) acc[p][o] = 0.f;

    const float* xb = x + (size_t)b * CIN * (H_ * W_);

    for (int cc = 0; cc < CHALF; cc += CB) {
        __syncthreads();
        // ---- stage x tile: CB channels, rows h0-1..h0+TH, cols w0-1..w0+TW ----
        for (int idx = tid; idx < CB * (TH + 2) * (TW + 2); idx += 256) {
            const int c   = idx / ((TH + 2) * (TW + 2));
            const int rem = idx - c * ((TH + 2) * (TW + 2));
            const int r   = rem / (TW + 2);
            const int col = rem - r * (TW + 2);
            const int hh = h0 - 1 + r;
            const int ww = w0 - 1 + col;
            float v = 0.f;
            if (hh >= 0 && hh < H_ && ww >= 0 && ww < W_)
                v = xb[(size_t)(c0 + cc + c) * (H_ * W_) + hh * W_ + ww];
            xs[c][r][col] = v;
        }
        // ---- stage weights: CB channels x 64 outs x 9 taps ----
        for (int idx = tid; idx < CB * COUT * 9; idx += 256) {
            const int c   = idx / (COUT * 9);
            const int rem = idx - c * (COUT * 9);
            const int o   = rem / 9;
            const int j   = rem - o * 9;
            ws[c][o][j] = weight[((size_t)o * CIN + (c0 + cc + c)) * 9 + j];
        }
        __syncthreads();

#pragma unroll
        for (int c = 0; c < CB; ++c) {
            // gated x patches for my 4 pixels
            float gx[4][9];
#pragma unroll
            for (int p = 0; p < 4; ++p) {
                const int r = hb + 2 * p;
#pragma unroll
                for (int i = 0; i < 3; ++i)
#pragma unroll
                    for (int j = 0; j < 3; ++j)
                        gx[p][i * 3 + j] = xs[c][r + i][wl + j] * gate[p][i * 3 + j];
            }
#pragma unroll
            for (int o = 0; o < 16; ++o) {
                const float* wp = &ws[c][og * 16 + o][0];
                float wv[9];
#pragma unroll
                for (int j = 0; j < 9; ++j) wv[j] = wp[j];   // wave-uniform broadcast
#pragma unroll
                for (int p = 0; p < 4; ++p)
#pragma unroll
                    for (int j = 0; j < 9; ++j)
                        acc[p][o] = fmaf(wv[j], gx[p][j], acc[p][o]);
            }
        }
    }

    // ---- write: atomicAdd (2 c-half blocks per address) ----
#pragma unroll
    for (int p = 0; p < 4; ++p) {
        const int hh = h0 + hb + 2 * p;
        const int ww = w0 + wl;
#pragma unroll
        for (int o = 0; o < 16; ++o) {
            const int oo = og * 16 + o;
            atomicAdd(&out[(((size_t)b * COUT + oo) * H_ + hh) * W_ + ww], acc[p][o]);
        }
    }
}

extern "C" void kernel_launch(void* const* d_in, const int* in_sizes, int n_in,
                              void* d_out, int out_size, void* d_ws, size_t ws_size,
                              hipStream_t stream) {
    const float* x      = (const float*)d_in[0];
    const float* depth  = (const float*)d_in[1];
    const float* weight = (const float*)d_in[2];
    float* out = (float*)d_out;

    // d_out is poisoned to 0xAA before every launch; zero it (atomicAdd target)
    hipMemsetAsync(out, 0, (size_t)out_size * sizeof(float), stream);

    dim3 grid(B_ * (H_ / TH) * (W_ / TW) * CS);   // 8*8*2*2 = 256 blocks
    dim3 block(256);
    depthconv_kernel<<<grid, block, 0, stream>>>(x, depth, weight, out);
}

// Round 2
// 335.678 us; speedup vs baseline: 2.1555x; 2.1555x over previous
//
#include <hip/hip_runtime.h>
#include <math.h>

#define B_    8
#define CIN   512
#define COUT  64
#define HW    4096     // 64*64
#define ALPHA 8.3f

#define RT    4        // rows per block tile
#define CS    4        // K-split across blocks
#define CPB   (CIN/CS) // 128 channels per block
#define CB    64       // channels staged per LDS phase
#define NCB   (CPB/CB) // 2 phases
#define XPITCH 72      // c-dim pitch in LDS (64 data + pad, 16B-aligned)

typedef short v8s  __attribute__((ext_vector_type(8)));
typedef float v16f __attribute__((ext_vector_type(16)));

static __device__ __forceinline__ unsigned short f2bf(float f) {
    unsigned int u = __float_as_uint(f);
    u = (u + 0x7fffu + ((u >> 16) & 1u)) >> 16;   // RNE
    return (unsigned short)u;
}

// Pre-swizzle weights into MFMA A-fragment order (bf16):
// wt[((tap*32 + ks)*2 + mt)*64 + lane][8] ; o = mt*32+(lane&31), c = ks*16+(lane>>5)*8+j
__global__ void prep_weights(const float* __restrict__ w, unsigned short* __restrict__ wt) {
    int i = blockIdx.x * 256 + threadIdx.x;
    if (i >= 9 * 32 * 2 * 64 * 8) return;
    int j    = i & 7;
    int lane = (i >> 3) & 63;
    int mt   = (i >> 9) & 1;
    int ks   = (i >> 10) & 31;
    int tap  = i >> 15;
    int o = mt * 32 + (lane & 31);
    int c = ks * 16 + (lane >> 5) * 8 + j;
    wt[i] = f2bf(w[(o * CIN + c) * 9 + tap]);
}

__global__ __launch_bounds__(256, 2)
void depthconv_mfma(const float* __restrict__ x,
                    const float* __restrict__ depth,
                    const unsigned short* __restrict__ wt,
                    float* __restrict__ out) {
    // xs[row 0..5][col 0..65][c 0..63 (pitch 72)] bf16 ; rows h0-1..h0+4, cols w-1..64
    __shared__ __align__(16) unsigned short xs[6 * 66 * XPITCH];   // 57 KB

    const int bx = blockIdx.x;
    const int cs = bx & 3;
    const int ht = (bx >> 2) & 15;
    const int b  = bx >> 6;
    const int h0 = ht * RT;

    const int tid  = threadIdx.x;
    const int wid  = tid >> 6;       // wave 0..3 -> output row h0+wid
    const int lane = tid & 63;
    const int l31  = lane & 31;
    const int half = lane >> 5;
    const int hq   = h0 + wid;

    // ---- gates: 2 col-tiles x 9 taps, fp32 (OOB depth = 0, matches jnp.pad) ----
    float g[2][9];
    const float* dp = depth + (size_t)b * HW;
#pragma unroll
    for (int nt = 0; nt < 2; ++nt) {
        const int wq = nt * 32 + l31;
        const float d0 = dp[hq * 64 + wq];
#pragma unroll
        for (int t = 0; t < 9; ++t) {
            const int di = t / 3 - 1, dj = t % 3 - 1;
            const int hn = hq + di, wn = wq + dj;
            float dn = 0.f;
            if (hn >= 0 && hn < 64 && wn >= 0 && wn < 64) dn = dp[hn * 64 + wn];
            g[nt][t] = __expf(-ALPHA * fabsf(d0 - dn));
        }
    }

    v16f acc[2][2];
#pragma unroll
    for (int mt = 0; mt < 2; ++mt)
#pragma unroll
        for (int nt = 0; nt < 2; ++nt)
#pragma unroll
            for (int r = 0; r < 16; ++r) acc[mt][nt][r] = 0.f;

    const float* xb = x + ((size_t)b * CIN + cs * CPB) * HW;

    for (int cb = 0; cb < NCB; ++cb) {
        __syncthreads();
        // ---- stage 64 channels: rows h0-1..h0+4, cols -1..64, bf16, c-innermost ----
        for (int i = tid; i < 6 * 66 * 16; i += 256) {
            const int col  = i % 66;             // lanes -> consecutive cols (coalesced)
            const int rest = i / 66;
            const int c4   = rest & 15;
            const int r    = rest >> 4;
            const int hh = h0 - 1 + r;
            const int ww = col - 1;
            const int cbase = cb * CB + c4 * 4;
            unsigned long long packed = 0ull;
            if (hh >= 0 && hh < 64 && ww >= 0 && ww < 64) {
                const float* p = xb + (size_t)cbase * HW + hh * 64 + ww;
                unsigned long long b0 = f2bf(p[0]);
                unsigned long long b1 = f2bf(p[HW]);
                unsigned long long b2 = f2bf(p[2 * HW]);
                unsigned long long b3 = f2bf(p[3 * HW]);
                packed = b0 | (b1 << 16) | (b2 << 32) | (b3 << 48);
            }
            *(unsigned long long*)&xs[(r * 66 + col) * XPITCH + c4 * 4] = packed;
        }
        __syncthreads();

#pragma unroll
        for (int tap = 0; tap < 9; ++tap) {
            const int di = tap / 3 - 1, dj = tap % 3 - 1;
            // ---- A fragments for this (cb, tap): register-resident, from global L2 ----
            v8s a[2][4];
#pragma unroll
            for (int kk = 0; kk < 4; ++kk) {
                const int ks = cs * 8 + cb * 4 + kk;
#pragma unroll
                for (int mt = 0; mt < 2; ++mt)
                    a[mt][kk] = *(const v8s*)&wt[(((tap * 32 + ks) * 2 + mt) * 64 + lane) * 8];
            }
            v16f pass[2][2];
#pragma unroll
            for (int mt = 0; mt < 2; ++mt)
#pragma unroll
                for (int nt = 0; nt < 2; ++nt)
#pragma unroll
                    for (int r = 0; r < 16; ++r) pass[mt][nt][r] = 0.f;

            const int rowb = (wid + 1 + di) * 66;
#pragma unroll
            for (int kk = 0; kk < 4; ++kk) {
#pragma unroll
                for (int nt = 0; nt < 2; ++nt) {
                    const int colx = nt * 32 + l31 + 1 + dj;
                    const v8s bv = *(const v8s*)&xs[(rowb + colx) * XPITCH + kk * 16 + half * 8];
#pragma unroll
                    for (int mt = 0; mt < 2; ++mt)
                        pass[mt][nt] = __builtin_amdgcn_mfma_f32_32x32x16_bf16(
                            a[mt][kk], bv, pass[mt][nt], 0, 0, 0);
                }
            }
            // ---- fold gate (per-lane scalar) into output accumulator ----
#pragma unroll
            for (int mt = 0; mt < 2; ++mt)
#pragma unroll
                for (int nt = 0; nt < 2; ++nt) {
                    const float gv = g[nt][tap];
#pragma unroll
                    for (int r = 0; r < 16; ++r)
                        acc[mt][nt][r] = fmaf(gv, pass[mt][nt][r], acc[mt][nt][r]);
                }
        }
    }

    // ---- epilogue: C layout col=lane&31, row=(reg&3)+8*(reg>>2)+4*half ----
    float* ob = out + (size_t)b * COUT * HW + hq * 64;
#pragma unroll
    for (int mt = 0; mt < 2; ++mt)
#pragma unroll
        for (int rg = 0; rg < 16; ++rg) {
            const int o = mt * 32 + (rg & 3) + 8 * (rg >> 2) + 4 * half;
#pragma unroll
            for (int nt = 0; nt < 2; ++nt)
                atomicAdd(&ob[(size_t)o * HW + nt * 32 + l31], acc[mt][nt][rg]);
        }
}

extern "C" void kernel_launch(void* const* d_in, const int* in_sizes, int n_in,
                              void* d_out, int out_size, void* d_ws, size_t ws_size,
                              hipStream_t stream) {
    const float* x      = (const float*)d_in[0];
    const float* depth  = (const float*)d_in[1];
    const float* weight = (const float*)d_in[2];
    float* out = (float*)d_out;
    unsigned short* wt = (unsigned short*)d_ws;   // 589,824 B of frag-major bf16 weights

    prep_weights<<<1152, 256, 0, stream>>>(weight, wt);
    hipMemsetAsync(out, 0, (size_t)out_size * sizeof(float), stream);
    depthconv_mfma<<<B_ * 16 * CS, 256, 0, stream>>>(x, depth, wt, out);
}